// Round 6
// baseline (121.520 us; speedup 1.0000x reference)
//
#include <hip/hip_runtime.h>
#include <hip/hip_bf16.h>

// Shapes (fixed by the problem)
#define NMOVES 4096
#define LW     15
#define DIM    1024
#define VOC    32
#define XROW   48    // [letter(32); pos(15); bias(1)] factored rows
#define KSPL   4     // proj K-split (256-wide chunks)
#define GSPL   8     // gram K-split (128-wide chunks)
#define PLSZ   (48 * DIM)        // one proj partial plane (fp32 elems)
#define ARM_MAGIC 0xA17C0DE1u    // arm pair = (M, ~M): uniform fill can't fake

typedef __attribute__((ext_vector_type(8))) short  short8;   // 8 bf16
typedef __attribute__((ext_vector_type(4))) float  floatx4;  // MFMA C/D

__device__ __forceinline__ unsigned short f2b(float f) {
  unsigned int x;
  __builtin_memcpy(&x, &f, 4);
  x = x + 0x7FFFu + ((x >> 16) & 1u);  // round-to-nearest-even
  return (unsigned short)(x >> 16);
}
__device__ __forceinline__ float b2f(unsigned short u) {
  unsigned int x = ((unsigned int)u) << 16;
  float f;
  __builtin_memcpy(&f, &x, 4);
  return f;
}
__device__ __forceinline__ short8 pk8(float4 a, float4 b) {
  short8 r;
  r[0] = (short)f2b(a.x); r[1] = (short)f2b(a.y);
  r[2] = (short)f2b(a.z); r[3] = (short)f2b(a.w);
  r[4] = (short)f2b(b.x); r[5] = (short)f2b(b.y);
  r[6] = (short)f2b(b.z); r[7] = (short)f2b(b.w);
  return r;
}
__device__ __forceinline__ float4 ld4(const float* p) {
  return *reinterpret_cast<const float4*>(p);
}

// ---------------------------------------------------------------------------
// K1: merged proj + gram + XvT with in-kernel flag sync (216 blocks, all
// co-resident on 256 CUs -> spin-wait cannot starve producers).
//  blocks 0..191 : factored projection, K-split 4 (round-5 body verbatim).
//                  block 0 zeroes G48+count then arms; each producer
//                  increments count after a release fence.
//  blocks 192..199: gram K-chunk partials, atomicAdd into G48[48][64]
//                  (wait for count==192 first).
//  blocks 200..215: XvT[n][k] = bf16(sum_p Xvp[p][k][n]) transpose.
// sync words: syncw[0]=count, syncw[2]=M, syncw[3]=~M.
// ---------------------------------------------------------------------------
__device__ __forceinline__ short8 gfrag(const float* __restrict__ X4,
                                        const float* __restrict__ bias,
                                        int row, int kc) {
  if (row < 47) {
    const float* r0 = X4 + (size_t)row * DIM + kc;
    float4 s0 = ld4(r0),            s1 = ld4(r0 + 4);
    float4 t0 = ld4(r0 + PLSZ),     t1 = ld4(r0 + PLSZ + 4);
    float4 u0 = ld4(r0 + 2 * PLSZ), u1 = ld4(r0 + 2 * PLSZ + 4);
    float4 v0 = ld4(r0 + 3 * PLSZ), v1 = ld4(r0 + 3 * PLSZ + 4);
    s0.x += t0.x + u0.x + v0.x; s0.y += t0.y + u0.y + v0.y;
    s0.z += t0.z + u0.z + v0.z; s0.w += t0.w + u0.w + v0.w;
    s1.x += t1.x + u1.x + v1.x; s1.y += t1.y + u1.y + v1.y;
    s1.z += t1.z + u1.z + v1.z; s1.w += t1.w + u1.w + v1.w;
    return pk8(s0, s1);
  } else if (row == 47) {
    return pk8(ld4(bias + kc), ld4(bias + kc + 4));
  }
  return (short8){0,0,0,0,0,0,0,0};
}

__global__ __launch_bounds__(256) void proj_gram(
    const float* __restrict__ letter, const float* __restrict__ pos,
    const float* __restrict__ Wq, const float* __restrict__ Wk,
    const float* __restrict__ Wv,
    const float* __restrict__ bq, const float* __restrict__ bk,
    float* __restrict__ Xp, float* __restrict__ G48,
    unsigned short* __restrict__ XvT, unsigned int* __restrict__ syncw) {
  const int bid = blockIdx.x;
  const int tid = threadIdx.x;

  if (bid < 192) {
    // ---- producer: projection block ----
    if (bid == 0) {  // zero G48 + count, then arm
#pragma unroll
      for (int i = 0; i < (XROW * 64) / 256; ++i) G48[i * 256 + tid] = 0.f;
      __syncthreads();
      if (tid == 0) {
        atomicExch(&syncw[0], 0u);
        __threadfence();
        atomicExch(&syncw[2], ARM_MAGIC);
        atomicExch(&syncw[3], ~ARM_MAGIC);
      }
    }

    const int p  = bid & 3;               // K chunk (256 wide)
    const int ny = (bid >> 2) & 15;       // col tile
    const int z  = bid >> 6;              // matrix
    const int kbase = p * 256;
    const int bn0   = ny * 64;
    const float* W = (z == 0) ? Wq : (z == 1) ? Wk : Wv;
    float*       O = Xp + (size_t)(z * KSPL + p) * PLSZ;

    const int lane = tid & 63;
    const int wave = tid >> 6;
    const int wr   = wave >> 1;
    const int wc   = wave & 1;
    const int quad = lane >> 4;
    const int l16  = lane & 15;

    const int rA0 = wr * 32 + l16;
    const int rA1 = rA0 + 16;
    const float* a0p = (rA0 < 32) ? letter + (size_t)rA0 * DIM
                     : (rA0 < 47) ? pos + (size_t)(rA0 - 32) * DIM : nullptr;
    const float* a1p = (rA1 < 32) ? letter + (size_t)rA1 * DIM
                     : (rA1 < 47) ? pos + (size_t)(rA1 - 32) * DIM : nullptr;
    const float* b0p = W + (size_t)(bn0 + wc * 32 + l16) * DIM;
    const float* b1p = b0p + (size_t)16 * DIM;

    floatx4 acc[2][2];
#pragma unroll
    for (int i = 0; i < 2; ++i)
#pragma unroll
      for (int j = 0; j < 2; ++j) acc[i][j] = (floatx4){0.f, 0.f, 0.f, 0.f};

    const short8 z8 = (short8){0,0,0,0,0,0,0,0};
#pragma unroll
    for (int kk = 0; kk < 256; kk += 32) {
      const int kc = kbase + kk + quad * 8;
      short8 a0 = a0p ? pk8(ld4(a0p + kc), ld4(a0p + kc + 4)) : z8;
      short8 a1 = a1p ? pk8(ld4(a1p + kc), ld4(a1p + kc + 4)) : z8;
      short8 b0 = pk8(ld4(b0p + kc), ld4(b0p + kc + 4));
      short8 b1 = pk8(ld4(b1p + kc), ld4(b1p + kc + 4));
      acc[0][0] = __builtin_amdgcn_mfma_f32_16x16x32_bf16(a0, b0, acc[0][0], 0, 0, 0);
      acc[0][1] = __builtin_amdgcn_mfma_f32_16x16x32_bf16(a0, b1, acc[0][1], 0, 0, 0);
      acc[1][0] = __builtin_amdgcn_mfma_f32_16x16x32_bf16(a1, b0, acc[1][0], 0, 0, 0);
      acc[1][1] = __builtin_amdgcn_mfma_f32_16x16x32_bf16(a1, b1, acc[1][1], 0, 0, 0);
    }

#pragma unroll
    for (int mi = 0; mi < 2; ++mi) {
#pragma unroll
      for (int ni = 0; ni < 2; ++ni) {
        const int gcol = bn0 + wc * 32 + ni * 16 + l16;
#pragma unroll
        for (int i = 0; i < 4; ++i) {
          const int grow = wr * 32 + mi * 16 + quad * 4 + i;
          if (grow < 47)
            O[(size_t)grow * DIM + gcol] = acc[mi][ni][i];
        }
      }
    }

    __syncthreads();      // all stores of this block issued
    if (tid == 0) {       // wait for arm (instant in practice), then signal
      while (atomicAdd(&syncw[2], 0u) != ARM_MAGIC ||
             atomicAdd(&syncw[3], 0u) != ~ARM_MAGIC) { }
      __threadfence();    // release: Xp/G48-zero stores visible
      atomicAdd(&syncw[0], 1u);
    }
  } else {
    // ---- consumer: gram (8) / XvT (16) blocks ----
    if (tid == 0) {
      while (atomicAdd(&syncw[2], 0u) != ARM_MAGIC ||
             atomicAdd(&syncw[3], 0u) != ~ARM_MAGIC) { }
      while (atomicAdd(&syncw[0], 0u) < 192u) { }
      __threadfence();    // acquire
    }
    __syncthreads();

    const int cb = bid - 192;
    if (cb < GSPL) {
      const int kbase = cb * 128;
      const int lane = tid & 63;
      const int wave = tid >> 6;
      const int wr   = wave >> 1;
      const int wc   = wave & 1;
      const int quad = lane >> 4;
      const int l16  = lane & 15;

      const float* Xq4 = Xp;                       // planes 0..3
      const float* Xk4 = Xp + (size_t)4 * PLSZ;    // planes 4..7
      const int rA0 = wr * 32 + l16, rA1 = rA0 + 16;
      const int rB0 = wc * 32 + l16, rB1 = rB0 + 16;

      floatx4 acc[2][2];
#pragma unroll
      for (int i = 0; i < 2; ++i)
#pragma unroll
        for (int j = 0; j < 2; ++j) acc[i][j] = (floatx4){0.f, 0.f, 0.f, 0.f};

#pragma unroll
      for (int kk = 0; kk < 128; kk += 32) {
        const int kc = kbase + kk + quad * 8;
        short8 a0 = gfrag(Xq4, bq, rA0, kc);
        short8 a1 = gfrag(Xq4, bq, rA1, kc);
        short8 b0 = gfrag(Xk4, bk, rB0, kc);
        short8 b1 = gfrag(Xk4, bk, rB1, kc);
        acc[0][0] = __builtin_amdgcn_mfma_f32_16x16x32_bf16(a0, b0, acc[0][0], 0, 0, 0);
        acc[0][1] = __builtin_amdgcn_mfma_f32_16x16x32_bf16(a0, b1, acc[0][1], 0, 0, 0);
        acc[1][0] = __builtin_amdgcn_mfma_f32_16x16x32_bf16(a1, b0, acc[1][0], 0, 0, 0);
        acc[1][1] = __builtin_amdgcn_mfma_f32_16x16x32_bf16(a1, b1, acc[1][1], 0, 0, 0);
      }

#pragma unroll
      for (int mi = 0; mi < 2; ++mi) {
#pragma unroll
        for (int ni = 0; ni < 2; ++ni) {
          const int gcol = wc * 32 + ni * 16 + l16;
#pragma unroll
          for (int i = 0; i < 4; ++i) {
            const int grow = wr * 32 + mi * 16 + quad * 4 + i;
            if (grow < XROW)
              atomicAdd(&G48[(size_t)grow * 64 + gcol], acc[mi][ni][i]);
          }
        }
      }
    } else {
      // XvT build: 16 blocks; lane<->n coalesced plane reads.
      const int n  = (cb - GSPL) * 64 + (tid & 63);
      const int kg = tid >> 6;
      const float* Xv4 = Xp + (size_t)8 * PLSZ;    // planes 8..11
#pragma unroll
      for (int s = 0; s < 4; ++s) {
        const int k0 = kg * 4 + s * 16;
        ushort4 o;
        unsigned short* oc = &o.x;
#pragma unroll
        for (int i = 0; i < 4; ++i) {
          const int k = k0 + i;
          float v = 0.f;
          if (k < 47) {
            const size_t off = (size_t)k * DIM + n;
            v = Xv4[off] + Xv4[off + PLSZ] + Xv4[off + 2 * PLSZ] +
                Xv4[off + 3 * PLSZ];
          }
          oc[i] = f2b(v);
        }
        *reinterpret_cast<ushort4*>(XvT + (size_t)n * 64 + k0) = o;
      }
    }
  }
}

// ---------------------------------------------------------------------------
// K2: fused coefficients + output GEMM (round-5 body verbatim).
// Grid (256, 4): block = 16 moves x 256 cols. Phase A: stage G48 into padded
// LDS, token gather, in-lane softmax, column-weight scatter, hi/lo bf16 split.
// Phase B: wave w = 16x64 out tile, A-frags from LDS, B from XvT, 16 MFMA.
// out = C·XvT + 30*bv.
// ---------------------------------------------------------------------------
__global__ __launch_bounds__(256) void attn_gemm(
    const void* __restrict__ tokens_raw, const float* __restrict__ G48,
    const unsigned short* __restrict__ XvT, const float* __restrict__ bv,
    float* __restrict__ out) {
  __shared__ float Gs[XROW * 65];       // padded LD=65: gather conflict-free
  __shared__ float Sm[16][LW][17];
  __shared__ float CL[16][64];
  __shared__ __attribute__((aligned(16))) unsigned short CLh[16 * 72];
  __shared__ __attribute__((aligned(16))) unsigned short CLl[16 * 72];
  __shared__ int   tokL[16][16];
  __shared__ int   is64_s;
  const int m0  = blockIdx.x * 16;
  const int cb0 = blockIdx.y * 256;
  const int tid = threadIdx.x;

  const unsigned int* u32 = (const unsigned int*)tokens_raw;
  if (tid < 64) {  // int64 tokens (<32) have all odd 32-bit words zero
    unsigned int v = u32[2 * tid + 1];
    unsigned long long nz = __ballot(v != 0);
    if (tid == 0) is64_s = (nz == 0ULL) ? 1 : 0;
  }
#pragma unroll
  for (int i = 0; i < 12; ++i) {        // stage 48x64 G into padded LDS
    const int idx = i * 256 + tid;
    Gs[(idx >> 6) * 65 + (idx & 63)] = G48[idx];
  }
  {
    const int g = tid >> 4, L = tid & 15;
#pragma unroll
    for (int i = 0; i < 4; ++i) CL[g][L * 4 + i] = 0.f;
  }
  __syncthreads();  // is64_s + Gs + CL visible

  if (tid < 16 * LW) {
    const int mv = tid / LW, j = tid - mv * LW;
    int t;
    if (is64_s) t = (int)((const long long*)tokens_raw)[(size_t)(m0 + mv) * LW + j];
    else        t = ((const int*)tokens_raw)[(size_t)(m0 + mv) * LW + j];
    tokL[mv][j] = t;
  }
  __syncthreads();

  const int g = tid >> 4;
  const int L = tid & 15;
  if (L < LW) {  // lane L = row l of move (m0+g)
    const int rb0 = tokL[g][L] * 65;
    const int rb1 = (32 + L) * 65;
    const int rb2 = (XROW - 1) * 65;
    float S[LW];
#pragma unroll
    for (int j = 0; j < LW; ++j) {
      const int c0 = tokL[g][j];
      const int c1 = 32 + j;
      S[j] = Gs[rb0 + c0] + Gs[rb1 + c0] + Gs[rb2 + c0]
           + Gs[rb0 + c1] + Gs[rb1 + c1] + Gs[rb2 + c1];
    }
    float mx = S[0];
#pragma unroll
    for (int j = 1; j < LW; ++j) mx = fmaxf(mx, S[j]);
    float sum = 0.f;
#pragma unroll
    for (int j = 0; j < LW; ++j) { S[j] = __expf(S[j] - mx); sum += S[j]; }
    const float inv = 1.0f / sum;
#pragma unroll
    for (int j = 0; j < LW; ++j) Sm[g][L][j] = S[j] * inv;
  }
  __syncthreads();

  if (L < LW) {  // lane L = column j: w_j = 2 * sum_l P[l][j], scatter
    float s = 0.f;
#pragma unroll
    for (int l = 0; l < LW; ++l) s += Sm[g][l][L];
    const float wj = 2.0f * s;
    atomicAdd(&CL[g][tokL[g][L]], wj);  // token slots may collide
    CL[g][32 + L] = wj;                 // position slots unique
  }
  __syncthreads();

  {  // hi/lo bf16 split into LDS (rows g, padded stride 72)
    float4 cv = *reinterpret_cast<const float4*>(&CL[g][L * 4]);
    ushort4 hi, lo;
    hi.x = f2b(cv.x); hi.y = f2b(cv.y); hi.z = f2b(cv.z); hi.w = f2b(cv.w);
    lo.x = f2b(cv.x - b2f(hi.x)); lo.y = f2b(cv.y - b2f(hi.y));
    lo.z = f2b(cv.z - b2f(hi.z)); lo.w = f2b(cv.w - b2f(hi.w));
    *reinterpret_cast<ushort4*>(CLh + g * 72 + L * 4) = hi;
    *reinterpret_cast<ushort4*>(CLl + g * 72 + L * 4) = lo;
  }
  __syncthreads();

  // Phase B: wave w covers cols cb0 + w*64 .. +63 of all 16 moves.
  const int lane = tid & 63;
  const int wave = tid >> 6;
  const int quad = lane >> 4;
  const int l16  = lane & 15;
  const int colb = cb0 + wave * 64;

  floatx4 acc[4];
#pragma unroll
  for (int i = 0; i < 4; ++i) acc[i] = (floatx4){0.f, 0.f, 0.f, 0.f};

#pragma unroll
  for (int ks = 0; ks < 64; ks += 32) {
    short8 ah = *reinterpret_cast<const short8*>(CLh + l16 * 72 + ks + quad * 8);
    short8 al = *reinterpret_cast<const short8*>(CLl + l16 * 72 + ks + quad * 8);
#pragma unroll
    for (int ni = 0; ni < 4; ++ni) {
      const unsigned short* B = XvT + (size_t)(colb + ni * 16 + l16) * 64;
      short8 b = *reinterpret_cast<const short8*>(B + ks + quad * 8);
      acc[ni] = __builtin_amdgcn_mfma_f32_16x16x32_bf16(ah, b, acc[ni], 0, 0, 0);
      acc[ni] = __builtin_amdgcn_mfma_f32_16x16x32_bf16(al, b, acc[ni], 0, 0, 0);
    }
  }

#pragma unroll
  for (int ni = 0; ni < 4; ++ni) {
    const int gcol = colb + ni * 16 + l16;
    const float bias30 = 30.0f * bv[gcol];
#pragma unroll
    for (int i = 0; i < 4; ++i) {
      out[(size_t)(m0 + quad * 4 + i) * DIM + gcol] = acc[ni][i] + bias30;
    }
  }
}

// ---------------------------------------------------------------------------
extern "C" void kernel_launch(void* const* d_in, const int* in_sizes, int n_in,
                              void* d_out, int out_size, void* d_ws, size_t ws_size,
                              hipStream_t stream) {
  const void*  tokens = d_in[0];
  const float* letter = (const float*)d_in[1];
  const float* pos    = (const float*)d_in[2];
  const float* Wq     = (const float*)d_in[3];
  const float* bq     = (const float*)d_in[4];
  const float* Wk     = (const float*)d_in[5];
  const float* bk     = (const float*)d_in[6];
  const float* Wv     = (const float*)d_in[7];
  const float* bv     = (const float*)d_in[8];
  float*       outp   = (float*)d_out;   // reference output dtype = float32

  char* ws = (char*)d_ws;
  const size_t XP_SZ  = (size_t)12 * PLSZ * 4;      // 12 planes  = 2.25 MB
  const size_t G_SZ   = (size_t)XROW * 64 * 4;      // 12 KB
  const size_t XVT_SZ = (size_t)DIM * 64 * 2;       // 128 KB
  float*          Xp    = (float*)(ws);
  float*          Gp    = (float*)(ws + XP_SZ);
  unsigned short* XvT   = (unsigned short*)(ws + XP_SZ + G_SZ);
  unsigned int*   syncw = (unsigned int*)(ws + XP_SZ + G_SZ + XVT_SZ);

  proj_gram<<<192 + GSPL + 16, 256, 0, stream>>>(letter, pos, Wq, Wk, Wv,
                                                 bq, bk, Xp, Gp, XvT, syncw);
  attn_gemm<<<dim3(NMOVES / 16, 4), 256, 0, stream>>>(tokens, Gp, XvT, bv, outp);
}

// Round 7
// 121.134 us; speedup vs baseline: 1.0032x; 1.0032x over previous
//
#include <hip/hip_runtime.h>
#include <hip/hip_bf16.h>

// Shapes (fixed by the problem)
#define NMOVES 4096
#define LW     15
#define DIM    1024
#define VOC    32
#define XROW   48    // [letter(32); pos(15); bias(1)] factored rows
#define KSPL   8     // proj K-split (128-wide chunks)
#define KCW    (DIM/KSPL)        // 128
#define GSPL   8     // gram K-split (128-wide chunks)
#define PLSZ   (48 * DIM)        // one proj partial plane (fp32 elems)

typedef __attribute__((ext_vector_type(8))) short  short8;   // 8 bf16
typedef __attribute__((ext_vector_type(4))) float  floatx4;  // MFMA C/D

__device__ __forceinline__ unsigned short f2b(float f) {
  unsigned int x;
  __builtin_memcpy(&x, &f, 4);
  x = x + 0x7FFFu + ((x >> 16) & 1u);  // round-to-nearest-even
  return (unsigned short)(x >> 16);
}
__device__ __forceinline__ float b2f(unsigned short u) {
  unsigned int x = ((unsigned int)u) << 16;
  float f;
  __builtin_memcpy(&f, &x, 4);
  return f;
}
__device__ __forceinline__ short8 pk8(float4 a, float4 b) {
  short8 r;
  r[0] = (short)f2b(a.x); r[1] = (short)f2b(a.y);
  r[2] = (short)f2b(a.z); r[3] = (short)f2b(a.w);
  r[4] = (short)f2b(b.x); r[5] = (short)f2b(b.y);
  r[6] = (short)f2b(b.z); r[7] = (short)f2b(b.w);
  return r;
}
__device__ __forceinline__ float4 ld4(const float* p) {
  return *reinterpret_cast<const float4*>(p);
}

// ---------------------------------------------------------------------------
// K1: factored projection, K-split 8, direct-fragment (no LDS, no barriers).
// Xp[z][p][r<47][1024] = sum_{k in chunk p} bf16(X[r][k])*bf16(W_z[c][k])
// X = [letter(32); pos(15)]; rows 47..63 zero. Grid (8,16,3)=384 blocks.
// Block (0,0,0) additionally zeroes the G48 accumulation plane (consumed by
// the NEXT kernel -> ordering guaranteed by the launch boundary).
// ---------------------------------------------------------------------------
__global__ __launch_bounds__(256) void proj_ksplit(
    const float* __restrict__ letter, const float* __restrict__ pos,
    const float* __restrict__ Wq, const float* __restrict__ Wk,
    const float* __restrict__ Wv, float* __restrict__ Xp,
    float* __restrict__ G48) {
  const int tid = threadIdx.x;
  if (blockIdx.x == 0 && blockIdx.y == 0 && blockIdx.z == 0) {
#pragma unroll
    for (int i = 0; i < (XROW * 64) / 256; ++i) G48[i * 256 + tid] = 0.f;
  }

  const int p     = blockIdx.x;        // K chunk (128 wide)
  const int bn0   = blockIdx.y * 64;   // col tile
  const int z     = blockIdx.z;
  const int kbase = p * KCW;
  const float* W = (z == 0) ? Wq : (z == 1) ? Wk : Wv;
  float*       O = Xp + (size_t)(z * KSPL + p) * PLSZ;

  const int lane = tid & 63;
  const int wave = tid >> 6;
  const int wr   = wave >> 1;
  const int wc   = wave & 1;
  const int quad = lane >> 4;
  const int l16  = lane & 15;

  // per-lane A row sources (row 0..31 letter, 32..46 pos, else zero)
  const int rA0 = wr * 32 + l16;
  const int rA1 = rA0 + 16;
  const float* a0p = (rA0 < 32) ? letter + (size_t)rA0 * DIM
                   : (rA0 < 47) ? pos + (size_t)(rA0 - 32) * DIM : nullptr;
  const float* a1p = (rA1 < 32) ? letter + (size_t)rA1 * DIM
                   : (rA1 < 47) ? pos + (size_t)(rA1 - 32) * DIM : nullptr;
  const float* b0p = W + (size_t)(bn0 + wc * 32 + l16) * DIM;
  const float* b1p = b0p + (size_t)16 * DIM;

  floatx4 acc[2][2];
#pragma unroll
  for (int i = 0; i < 2; ++i)
#pragma unroll
    for (int j = 0; j < 2; ++j) acc[i][j] = (floatx4){0.f, 0.f, 0.f, 0.f};

  const short8 z8 = (short8){0,0,0,0,0,0,0,0};
#pragma unroll
  for (int kk = 0; kk < KCW; kk += 32) {
    const int kc = kbase + kk + quad * 8;
    short8 a0 = a0p ? pk8(ld4(a0p + kc), ld4(a0p + kc + 4)) : z8;
    short8 a1 = a1p ? pk8(ld4(a1p + kc), ld4(a1p + kc + 4)) : z8;
    short8 b0 = pk8(ld4(b0p + kc), ld4(b0p + kc + 4));
    short8 b1 = pk8(ld4(b1p + kc), ld4(b1p + kc + 4));
    acc[0][0] = __builtin_amdgcn_mfma_f32_16x16x32_bf16(a0, b0, acc[0][0], 0, 0, 0);
    acc[0][1] = __builtin_amdgcn_mfma_f32_16x16x32_bf16(a0, b1, acc[0][1], 0, 0, 0);
    acc[1][0] = __builtin_amdgcn_mfma_f32_16x16x32_bf16(a1, b0, acc[1][0], 0, 0, 0);
    acc[1][1] = __builtin_amdgcn_mfma_f32_16x16x32_bf16(a1, b1, acc[1][1], 0, 0, 0);
  }

#pragma unroll
  for (int mi = 0; mi < 2; ++mi) {
#pragma unroll
    for (int ni = 0; ni < 2; ++ni) {
      const int gcol = bn0 + wc * 32 + ni * 16 + l16;
#pragma unroll
      for (int i = 0; i < 4; ++i) {
        const int grow = wr * 32 + mi * 16 + quad * 4 + i;
        if (grow < 47)
          O[(size_t)grow * DIM + gcol] = acc[mi][ni][i];
      }
    }
  }
}

// ---------------------------------------------------------------------------
// K2: fused gram (K-split 8, blocks 0..7) + XvT transpose (blocks 8..23).
// Gram: atomicAdd into single G48[48][64] = [Xq;bq]·[Xk;bk]^T, per-K-chunk
//       partials; A/B fragments built by summing the 8 proj planes in-regs.
// XvT:  XvT[n][k] = bf16(sum_p Xvp[p][k][n]), k<47 else 0.  (1024 x 64)
// No LDS, no barriers anywhere.
// ---------------------------------------------------------------------------
__device__ __forceinline__ short8 gfrag(const float* __restrict__ Xk8,
                                        const float* __restrict__ bias,
                                        int row, int kc) {
  if (row < 47) {
    const float* r0 = Xk8 + (size_t)row * DIM + kc;
    float4 s0 = ld4(r0), s1 = ld4(r0 + 4);
#pragma unroll
    for (int p = 1; p < KSPL; ++p) {
      float4 t0 = ld4(r0 + (size_t)p * PLSZ);
      float4 t1 = ld4(r0 + (size_t)p * PLSZ + 4);
      s0.x += t0.x; s0.y += t0.y; s0.z += t0.z; s0.w += t0.w;
      s1.x += t1.x; s1.y += t1.y; s1.z += t1.z; s1.w += t1.w;
    }
    return pk8(s0, s1);
  } else if (row == 47) {
    return pk8(ld4(bias + kc), ld4(bias + kc + 4));
  }
  return (short8){0,0,0,0,0,0,0,0};
}

__global__ __launch_bounds__(256) void gram_vexp(
    const float* __restrict__ Xp,
    const float* __restrict__ bq, const float* __restrict__ bk,
    float* __restrict__ G48, unsigned short* __restrict__ XvT) {
  const int bid = blockIdx.x;
  const int tid = threadIdx.x;

  if (bid < GSPL) {
    const int kbase = bid * 128;
    const int lane = tid & 63;
    const int wave = tid >> 6;
    const int wr   = wave >> 1;
    const int wc   = wave & 1;
    const int quad = lane >> 4;
    const int l16  = lane & 15;

    const float* Xq8 = Xp;                            // planes 0..7
    const float* Xk8 = Xp + (size_t)KSPL * PLSZ;      // planes 8..15
    const int rA0 = wr * 32 + l16, rA1 = rA0 + 16;
    const int rB0 = wc * 32 + l16, rB1 = rB0 + 16;

    floatx4 acc[2][2];
#pragma unroll
    for (int i = 0; i < 2; ++i)
#pragma unroll
      for (int j = 0; j < 2; ++j) acc[i][j] = (floatx4){0.f, 0.f, 0.f, 0.f};

#pragma unroll
    for (int kk = 0; kk < 128; kk += 32) {
      const int kc = kbase + kk + quad * 8;
      short8 a0 = gfrag(Xq8, bq, rA0, kc);
      short8 a1 = gfrag(Xq8, bq, rA1, kc);
      short8 b0 = gfrag(Xk8, bk, rB0, kc);
      short8 b1 = gfrag(Xk8, bk, rB1, kc);
      acc[0][0] = __builtin_amdgcn_mfma_f32_16x16x32_bf16(a0, b0, acc[0][0], 0, 0, 0);
      acc[0][1] = __builtin_amdgcn_mfma_f32_16x16x32_bf16(a0, b1, acc[0][1], 0, 0, 0);
      acc[1][0] = __builtin_amdgcn_mfma_f32_16x16x32_bf16(a1, b0, acc[1][0], 0, 0, 0);
      acc[1][1] = __builtin_amdgcn_mfma_f32_16x16x32_bf16(a1, b1, acc[1][1], 0, 0, 0);
    }

#pragma unroll
    for (int mi = 0; mi < 2; ++mi) {
#pragma unroll
      for (int ni = 0; ni < 2; ++ni) {
        const int gcol = wc * 32 + ni * 16 + l16;
#pragma unroll
        for (int i = 0; i < 4; ++i) {
          const int grow = wr * 32 + mi * 16 + quad * 4 + i;
          if (grow < XROW)
            atomicAdd(&G48[(size_t)grow * 64 + gcol], acc[mi][ni][i]);
        }
      }
    }
  } else {
    // XvT build: 16 blocks; lane<->n coalesced plane reads.
    const int n  = (bid - GSPL) * 64 + (tid & 63);
    const int kg = tid >> 6;
    const float* Xv8 = Xp + (size_t)2 * KSPL * PLSZ;  // planes 16..23
#pragma unroll
    for (int s = 0; s < 4; ++s) {
      const int k0 = kg * 4 + s * 16;
      ushort4 o;
      unsigned short* oc = &o.x;
#pragma unroll
      for (int i = 0; i < 4; ++i) {
        const int k = k0 + i;
        float v = 0.f;
        if (k < 47) {
          const size_t off = (size_t)k * DIM + n;
#pragma unroll
          for (int pp = 0; pp < KSPL; ++pp) v += Xv8[off + (size_t)pp * PLSZ];
        }
        oc[i] = f2b(v);
      }
      *reinterpret_cast<ushort4*>(XvT + (size_t)n * 64 + k0) = o;
    }
  }
}

// ---------------------------------------------------------------------------
// K3: fused coefficients + output GEMM (round-5 body verbatim).
// Grid (256, 4): block = 16 moves x 256 cols. Phase A: stage G48 into padded
// LDS, token gather, in-lane softmax, column-weight scatter, hi/lo bf16 split.
// Phase B: wave w = 16x64 out tile, A-frags from LDS, B from XvT, 16 MFMA.
// out = C·XvT + 30*bv.
// ---------------------------------------------------------------------------
__global__ __launch_bounds__(256) void attn_gemm(
    const void* __restrict__ tokens_raw, const float* __restrict__ G48,
    const unsigned short* __restrict__ XvT, const float* __restrict__ bv,
    float* __restrict__ out) {
  __shared__ float Gs[XROW * 65];       // padded LD=65: gather conflict-free
  __shared__ float Sm[16][LW][17];
  __shared__ float CL[16][64];
  __shared__ __attribute__((aligned(16))) unsigned short CLh[16 * 72];
  __shared__ __attribute__((aligned(16))) unsigned short CLl[16 * 72];
  __shared__ int   tokL[16][16];
  __shared__ int   is64_s;
  const int m0  = blockIdx.x * 16;
  const int cb0 = blockIdx.y * 256;
  const int tid = threadIdx.x;

  const unsigned int* u32 = (const unsigned int*)tokens_raw;
  if (tid < 64) {  // int64 tokens (<32) have all odd 32-bit words zero
    unsigned int v = u32[2 * tid + 1];
    unsigned long long nz = __ballot(v != 0);
    if (tid == 0) is64_s = (nz == 0ULL) ? 1 : 0;
  }
#pragma unroll
  for (int i = 0; i < 12; ++i) {        // stage 48x64 G into padded LDS
    const int idx = i * 256 + tid;
    Gs[(idx >> 6) * 65 + (idx & 63)] = G48[idx];
  }
  {
    const int g = tid >> 4, L = tid & 15;
#pragma unroll
    for (int i = 0; i < 4; ++i) CL[g][L * 4 + i] = 0.f;
  }
  __syncthreads();  // is64_s + Gs + CL visible

  if (tid < 16 * LW) {
    const int mv = tid / LW, j = tid - mv * LW;
    int t;
    if (is64_s) t = (int)((const long long*)tokens_raw)[(size_t)(m0 + mv) * LW + j];
    else        t = ((const int*)tokens_raw)[(size_t)(m0 + mv) * LW + j];
    tokL[mv][j] = t;
  }
  __syncthreads();

  const int g = tid >> 4;
  const int L = tid & 15;
  if (L < LW) {  // lane L = row l of move (m0+g)
    const int rb0 = tokL[g][L] * 65;
    const int rb1 = (32 + L) * 65;
    const int rb2 = (XROW - 1) * 65;
    float S[LW];
#pragma unroll
    for (int j = 0; j < LW; ++j) {
      const int c0 = tokL[g][j];
      const int c1 = 32 + j;
      S[j] = Gs[rb0 + c0] + Gs[rb1 + c0] + Gs[rb2 + c0]
           + Gs[rb0 + c1] + Gs[rb1 + c1] + Gs[rb2 + c1];
    }
    float mx = S[0];
#pragma unroll
    for (int j = 1; j < LW; ++j) mx = fmaxf(mx, S[j]);
    float sum = 0.f;
#pragma unroll
    for (int j = 0; j < LW; ++j) { S[j] = __expf(S[j] - mx); sum += S[j]; }
    const float inv = 1.0f / sum;
#pragma unroll
    for (int j = 0; j < LW; ++j) Sm[g][L][j] = S[j] * inv;
  }
  __syncthreads();

  if (L < LW) {  // lane L = column j: w_j = 2 * sum_l P[l][j], scatter
    float s = 0.f;
#pragma unroll
    for (int l = 0; l < LW; ++l) s += Sm[g][l][L];
    const float wj = 2.0f * s;
    atomicAdd(&CL[g][tokL[g][L]], wj);  // token slots may collide
    CL[g][32 + L] = wj;                 // position slots unique
  }
  __syncthreads();

  {  // hi/lo bf16 split into LDS (rows g, padded stride 72)
    float4 cv = *reinterpret_cast<const float4*>(&CL[g][L * 4]);
    ushort4 hi, lo;
    hi.x = f2b(cv.x); hi.y = f2b(cv.y); hi.z = f2b(cv.z); hi.w = f2b(cv.w);
    lo.x = f2b(cv.x - b2f(hi.x)); lo.y = f2b(cv.y - b2f(hi.y));
    lo.z = f2b(cv.z - b2f(hi.z)); lo.w = f2b(cv.w - b2f(hi.w));
    *reinterpret_cast<ushort4*>(CLh + g * 72 + L * 4) = hi;
    *reinterpret_cast<ushort4*>(CLl + g * 72 + L * 4) = lo;
  }
  __syncthreads();

  // Phase B: wave w covers cols cb0 + w*64 .. +63 of all 16 moves.
  const int lane = tid & 63;
  const int wave = tid >> 6;
  const int quad = lane >> 4;
  const int l16  = lane & 15;
  const int colb = cb0 + wave * 64;

  floatx4 acc[4];
#pragma unroll
  for (int i = 0; i < 4; ++i) acc[i] = (floatx4){0.f, 0.f, 0.f, 0.f};

#pragma unroll
  for (int ks = 0; ks < 64; ks += 32) {
    short8 ah = *reinterpret_cast<const short8*>(CLh + l16 * 72 + ks + quad * 8);
    short8 al = *reinterpret_cast<const short8*>(CLl + l16 * 72 + ks + quad * 8);
#pragma unroll
    for (int ni = 0; ni < 4; ++ni) {
      const unsigned short* B = XvT + (size_t)(colb + ni * 16 + l16) * 64;
      short8 b = *reinterpret_cast<const short8*>(B + ks + quad * 8);
      acc[ni] = __builtin_amdgcn_mfma_f32_16x16x32_bf16(ah, b, acc[ni], 0, 0, 0);
      acc[ni] = __builtin_amdgcn_mfma_f32_16x16x32_bf16(al, b, acc[ni], 0, 0, 0);
    }
  }

#pragma unroll
  for (int ni = 0; ni < 4; ++ni) {
    const int gcol = colb + ni * 16 + l16;
    const float bias30 = 30.0f * bv[gcol];
#pragma unroll
    for (int i = 0; i < 4; ++i) {
      out[(size_t)(m0 + quad * 4 + i) * DIM + gcol] = acc[ni][i] + bias30;
    }
  }
}

// ---------------------------------------------------------------------------
extern "C" void kernel_launch(void* const* d_in, const int* in_sizes, int n_in,
                              void* d_out, int out_size, void* d_ws, size_t ws_size,
                              hipStream_t stream) {
  const void*  tokens = d_in[0];
  const float* letter = (const float*)d_in[1];
  const float* pos    = (const float*)d_in[2];
  const float* Wq     = (const float*)d_in[3];
  const float* bq     = (const float*)d_in[4];
  const float* Wk     = (const float*)d_in[5];
  const float* bk     = (const float*)d_in[6];
  const float* Wv     = (const float*)d_in[7];
  const float* bv     = (const float*)d_in[8];
  float*       outp   = (float*)d_out;   // reference output dtype = float32

  char* ws = (char*)d_ws;
  const size_t XP_SZ  = (size_t)3 * KSPL * PLSZ * 4;  // 24 planes = 4.5 MB
  const size_t G_SZ   = (size_t)XROW * 64 * 4;        // 12 KB
  float*          Xp  = (float*)(ws);
  float*          Gp  = (float*)(ws + XP_SZ);
  unsigned short* XvT = (unsigned short*)(ws + XP_SZ + G_SZ);

  proj_ksplit<<<dim3(KSPL, 16, 3), 256, 0, stream>>>(letter, pos, Wq, Wk, Wv,
                                                     Xp, Gp);
  gram_vexp<<<GSPL + 16, 256, 0, stream>>>(Xp, bq, bk, Gp, XvT);
  attn_gemm<<<dim3(NMOVES / 16, 4), 256, 0, stream>>>(tokens, Gp, XvT, bv, outp);
}

// Round 8
// 116.822 us; speedup vs baseline: 1.0402x; 1.0369x over previous
//
#include <hip/hip_runtime.h>
#include <hip/hip_bf16.h>

// Shapes (fixed by the problem)
#define NMOVES 4096
#define LW     15
#define DIM    1024
#define VOC    32
#define XROW   48    // [letter(32); pos(15); bias(1)] factored rows
#define KSPL   4     // proj K-split (256-wide chunks)
#define GSPL   8     // gram K-split (128-wide chunks)
#define PLSZ   (48 * DIM)        // one proj partial plane (fp32 elems)

typedef __attribute__((ext_vector_type(8))) short  short8;   // 8 bf16
typedef __attribute__((ext_vector_type(4))) float  floatx4;  // MFMA C/D

__device__ __forceinline__ unsigned short f2b(float f) {
  unsigned int x;
  __builtin_memcpy(&x, &f, 4);
  x = x + 0x7FFFu + ((x >> 16) & 1u);  // round-to-nearest-even
  return (unsigned short)(x >> 16);
}
__device__ __forceinline__ float b2f(unsigned short u) {
  unsigned int x = ((unsigned int)u) << 16;
  float f;
  __builtin_memcpy(&f, &x, 4);
  return f;
}
__device__ __forceinline__ short8 pk8(float4 a, float4 b) {
  short8 r;
  r[0] = (short)f2b(a.x); r[1] = (short)f2b(a.y);
  r[2] = (short)f2b(a.z); r[3] = (short)f2b(a.w);
  r[4] = (short)f2b(b.x); r[5] = (short)f2b(b.y);
  r[6] = (short)f2b(b.z); r[7] = (short)f2b(b.w);
  return r;
}
__device__ __forceinline__ float4 ld4(const float* p) {
  return *reinterpret_cast<const float4*>(p);
}

// ---------------------------------------------------------------------------
// K1: factored projection, K-split 4, direct-fragment (no LDS, no barriers).
// Xp[z][p][r<47][1024] = sum_{k in chunk p} bf16(X[r][k])*bf16(W_z[c][k])
// X = [letter(32); pos(15)]; rows 47..63 zero. Grid (4,16,3), 256 thr.
// Block (0,0,0) additionally zeroes the G48 accumulation plane (consumed by
// the NEXT kernel -> ordering guaranteed by the launch boundary).
// ---------------------------------------------------------------------------
__global__ __launch_bounds__(256) void proj_ksplit(
    const float* __restrict__ letter, const float* __restrict__ pos,
    const float* __restrict__ Wq, const float* __restrict__ Wk,
    const float* __restrict__ Wv, float* __restrict__ Xp,
    float* __restrict__ G48) {
  const int tid = threadIdx.x;
  if (blockIdx.x == 0 && blockIdx.y == 0 && blockIdx.z == 0) {
#pragma unroll
    for (int i = 0; i < (XROW * 64) / 256; ++i) G48[i * 256 + tid] = 0.f;
  }

  const int p     = blockIdx.x;        // K chunk (256 wide)
  const int bn0   = blockIdx.y * 64;   // col tile
  const int z     = blockIdx.z;
  const int kbase = p * 256;
  const float* W = (z == 0) ? Wq : (z == 1) ? Wk : Wv;
  float*       O = Xp + (size_t)(z * KSPL + p) * PLSZ;

  const int lane = tid & 63;
  const int wave = tid >> 6;
  const int wr   = wave >> 1;
  const int wc   = wave & 1;
  const int quad = lane >> 4;
  const int l16  = lane & 15;

  // per-lane A row sources (row 0..31 letter, 32..46 pos, else zero)
  const int rA0 = wr * 32 + l16;
  const int rA1 = rA0 + 16;
  const float* a0p = (rA0 < 32) ? letter + (size_t)rA0 * DIM
                   : (rA0 < 47) ? pos + (size_t)(rA0 - 32) * DIM : nullptr;
  const float* a1p = (rA1 < 32) ? letter + (size_t)rA1 * DIM
                   : (rA1 < 47) ? pos + (size_t)(rA1 - 32) * DIM : nullptr;
  const float* b0p = W + (size_t)(bn0 + wc * 32 + l16) * DIM;
  const float* b1p = b0p + (size_t)16 * DIM;

  floatx4 acc[2][2];
#pragma unroll
  for (int i = 0; i < 2; ++i)
#pragma unroll
    for (int j = 0; j < 2; ++j) acc[i][j] = (floatx4){0.f, 0.f, 0.f, 0.f};

  const short8 z8 = (short8){0,0,0,0,0,0,0,0};
#pragma unroll
  for (int kk = 0; kk < 256; kk += 32) {
    const int kc = kbase + kk + quad * 8;
    short8 a0 = a0p ? pk8(ld4(a0p + kc), ld4(a0p + kc + 4)) : z8;
    short8 a1 = a1p ? pk8(ld4(a1p + kc), ld4(a1p + kc + 4)) : z8;
    short8 b0 = pk8(ld4(b0p + kc), ld4(b0p + kc + 4));
    short8 b1 = pk8(ld4(b1p + kc), ld4(b1p + kc + 4));
    acc[0][0] = __builtin_amdgcn_mfma_f32_16x16x32_bf16(a0, b0, acc[0][0], 0, 0, 0);
    acc[0][1] = __builtin_amdgcn_mfma_f32_16x16x32_bf16(a0, b1, acc[0][1], 0, 0, 0);
    acc[1][0] = __builtin_amdgcn_mfma_f32_16x16x32_bf16(a1, b0, acc[1][0], 0, 0, 0);
    acc[1][1] = __builtin_amdgcn_mfma_f32_16x16x32_bf16(a1, b1, acc[1][1], 0, 0, 0);
  }

#pragma unroll
  for (int mi = 0; mi < 2; ++mi) {
#pragma unroll
    for (int ni = 0; ni < 2; ++ni) {
      const int gcol = bn0 + wc * 32 + ni * 16 + l16;
#pragma unroll
      for (int i = 0; i < 4; ++i) {
        const int grow = wr * 32 + mi * 16 + quad * 4 + i;
        if (grow < 47)
          O[(size_t)grow * DIM + gcol] = acc[mi][ni][i];
      }
    }
  }
}

// ---------------------------------------------------------------------------
// K2: fused gram (K-split 8, blocks 0..7) + XvT transpose (blocks 8..23).
// Gram: atomicAdd into single G48[48][64] = [Xq;bq]·[Xk;bk]^T, per-K-chunk
//       partials; A/B fragments built by summing the 4 proj planes in-regs.
// XvT:  XvT[n][k] = bf16(sum_p Xvp[p][k][n]), k<47 else 0.  (1024 x 64)
// No LDS, no barriers anywhere.
// ---------------------------------------------------------------------------
__device__ __forceinline__ short8 gfrag(const float* __restrict__ X4,
                                        const float* __restrict__ bias,
                                        int row, int kc) {
  if (row < 47) {
    const float* r0 = X4 + (size_t)row * DIM + kc;
    float4 s0 = ld4(r0),            s1 = ld4(r0 + 4);
    float4 t0 = ld4(r0 + PLSZ),     t1 = ld4(r0 + PLSZ + 4);
    float4 u0 = ld4(r0 + 2 * PLSZ), u1 = ld4(r0 + 2 * PLSZ + 4);
    float4 v0 = ld4(r0 + 3 * PLSZ), v1 = ld4(r0 + 3 * PLSZ + 4);
    s0.x += t0.x + u0.x + v0.x; s0.y += t0.y + u0.y + v0.y;
    s0.z += t0.z + u0.z + v0.z; s0.w += t0.w + u0.w + v0.w;
    s1.x += t1.x + u1.x + v1.x; s1.y += t1.y + u1.y + v1.y;
    s1.z += t1.z + u1.z + v1.z; s1.w += t1.w + u1.w + v1.w;
    return pk8(s0, s1);
  } else if (row == 47) {
    return pk8(ld4(bias + kc), ld4(bias + kc + 4));
  }
  return (short8){0,0,0,0,0,0,0,0};
}

__global__ __launch_bounds__(256) void gram_vexp(
    const float* __restrict__ Xp,
    const float* __restrict__ bq, const float* __restrict__ bk,
    float* __restrict__ G48, unsigned short* __restrict__ XvT) {
  const int bid = blockIdx.x;
  const int tid = threadIdx.x;

  if (bid < GSPL) {
    const int kbase = bid * 128;
    const int lane = tid & 63;
    const int wave = tid >> 6;
    const int wr   = wave >> 1;
    const int wc   = wave & 1;
    const int quad = lane >> 4;
    const int l16  = lane & 15;

    const float* Xq4 = Xp;                       // planes 0..3
    const float* Xk4 = Xp + (size_t)4 * PLSZ;    // planes 4..7
    const int rA0 = wr * 32 + l16, rA1 = rA0 + 16;
    const int rB0 = wc * 32 + l16, rB1 = rB0 + 16;

    floatx4 acc[2][2];
#pragma unroll
    for (int i = 0; i < 2; ++i)
#pragma unroll
      for (int j = 0; j < 2; ++j) acc[i][j] = (floatx4){0.f, 0.f, 0.f, 0.f};

#pragma unroll
    for (int kk = 0; kk < 128; kk += 32) {
      const int kc = kbase + kk + quad * 8;
      short8 a0 = gfrag(Xq4, bq, rA0, kc);
      short8 a1 = gfrag(Xq4, bq, rA1, kc);
      short8 b0 = gfrag(Xk4, bk, rB0, kc);
      short8 b1 = gfrag(Xk4, bk, rB1, kc);
      acc[0][0] = __builtin_amdgcn_mfma_f32_16x16x32_bf16(a0, b0, acc[0][0], 0, 0, 0);
      acc[0][1] = __builtin_amdgcn_mfma_f32_16x16x32_bf16(a0, b1, acc[0][1], 0, 0, 0);
      acc[1][0] = __builtin_amdgcn_mfma_f32_16x16x32_bf16(a1, b0, acc[1][0], 0, 0, 0);
      acc[1][1] = __builtin_amdgcn_mfma_f32_16x16x32_bf16(a1, b1, acc[1][1], 0, 0, 0);
    }

#pragma unroll
    for (int mi = 0; mi < 2; ++mi) {
#pragma unroll
      for (int ni = 0; ni < 2; ++ni) {
        const int gcol = wc * 32 + ni * 16 + l16;
#pragma unroll
        for (int i = 0; i < 4; ++i) {
          const int grow = wr * 32 + mi * 16 + quad * 4 + i;
          if (grow < XROW)
            atomicAdd(&G48[(size_t)grow * 64 + gcol], acc[mi][ni][i]);
        }
      }
    }
  } else {
    // XvT build: 16 blocks; lane<->n coalesced plane reads.
    const int n  = (bid - GSPL) * 64 + (tid & 63);
    const int kg = tid >> 6;
    const float* Xv4 = Xp + (size_t)8 * PLSZ;    // planes 8..11
#pragma unroll
    for (int s = 0; s < 4; ++s) {
      const int k0 = kg * 4 + s * 16;
      ushort4 o;
      unsigned short* oc = &o.x;
#pragma unroll
      for (int i = 0; i < 4; ++i) {
        const int k = k0 + i;
        float v = 0.f;
        if (k < 47) {
          const size_t off = (size_t)k * DIM + n;
          v = Xv4[off] + Xv4[off + PLSZ] + Xv4[off + 2 * PLSZ] +
              Xv4[off + 3 * PLSZ];
        }
        oc[i] = f2b(v);
      }
      *reinterpret_cast<ushort4*>(XvT + (size_t)n * 64 + k0) = o;
    }
  }
}

// ---------------------------------------------------------------------------
// K3: fused coefficients + output GEMM. Grid (256, 4): block = 16 moves x
// 256 cols. XvT B-fragments are hoisted to the top (loop-invariant, L2-hit)
// so their latency hides under Phase A. Phase A: stage G48 into padded LDS,
// token gather, in-lane softmax, column-weight scatter, hi/lo bf16 split.
// Phase B: wave w = 16x64 out tile, A-frags from LDS, 16 MFMA.
// out = C·XvT + 30*bv.
// ---------------------------------------------------------------------------
__global__ __launch_bounds__(256) void attn_gemm(
    const void* __restrict__ tokens_raw, const float* __restrict__ G48,
    const unsigned short* __restrict__ XvT, const float* __restrict__ bv,
    float* __restrict__ out) {
  __shared__ float Gs[XROW * 65];       // padded LD=65: gather conflict-free
  __shared__ float Sm[16][LW][17];
  __shared__ float CL[16][64];
  __shared__ __attribute__((aligned(16))) unsigned short CLh[16 * 72];
  __shared__ __attribute__((aligned(16))) unsigned short CLl[16 * 72];
  __shared__ int   tokL[16][16];
  __shared__ int   is64_s;
  const int m0  = blockIdx.x * 16;
  const int cb0 = blockIdx.y * 256;
  const int tid = threadIdx.x;

  // ---- hoisted Phase-B geometry + loop-invariant B loads (issue early) ----
  const int lane = tid & 63;
  const int wave = tid >> 6;
  const int quad = lane >> 4;
  const int l16  = lane & 15;
  const int colb = cb0 + wave * 64;

  short8 bfrag[2][4];
#pragma unroll
  for (int ksi = 0; ksi < 2; ++ksi)
#pragma unroll
    for (int ni = 0; ni < 4; ++ni) {
      const unsigned short* B = XvT + (size_t)(colb + ni * 16 + l16) * 64;
      bfrag[ksi][ni] = *reinterpret_cast<const short8*>(B + ksi * 32 + quad * 8);
    }

  const unsigned int* u32 = (const unsigned int*)tokens_raw;
  if (tid < 64) {  // int64 tokens (<32) have all odd 32-bit words zero
    unsigned int v = u32[2 * tid + 1];
    unsigned long long nz = __ballot(v != 0);
    if (tid == 0) is64_s = (nz == 0ULL) ? 1 : 0;
  }
#pragma unroll
  for (int i = 0; i < 12; ++i) {        // stage 48x64 G into padded LDS
    const int idx = i * 256 + tid;
    Gs[(idx >> 6) * 65 + (idx & 63)] = G48[idx];
  }
  {
    const int g = tid >> 4, L = tid & 15;
#pragma unroll
    for (int i = 0; i < 4; ++i) CL[g][L * 4 + i] = 0.f;
  }
  __syncthreads();  // is64_s + Gs + CL visible

  if (tid < 16 * LW) {
    const int mv = tid / LW, j = tid - mv * LW;
    int t;
    if (is64_s) t = (int)((const long long*)tokens_raw)[(size_t)(m0 + mv) * LW + j];
    else        t = ((const int*)tokens_raw)[(size_t)(m0 + mv) * LW + j];
    tokL[mv][j] = t;
  }
  __syncthreads();

  const int g = tid >> 4;
  const int L = tid & 15;
  if (L < LW) {  // lane L = row l of move (m0+g)
    const int rb0 = tokL[g][L] * 65;
    const int rb1 = (32 + L) * 65;
    const int rb2 = (XROW - 1) * 65;
    float S[LW];
#pragma unroll
    for (int j = 0; j < LW; ++j) {
      const int c0 = tokL[g][j];
      const int c1 = 32 + j;
      S[j] = Gs[rb0 + c0] + Gs[rb1 + c0] + Gs[rb2 + c0]
           + Gs[rb0 + c1] + Gs[rb1 + c1] + Gs[rb2 + c1];
    }
    float mx = S[0];
#pragma unroll
    for (int j = 1; j < LW; ++j) mx = fmaxf(mx, S[j]);
    float sum = 0.f;
#pragma unroll
    for (int j = 0; j < LW; ++j) { S[j] = __expf(S[j] - mx); sum += S[j]; }
    const float inv = 1.0f / sum;
#pragma unroll
    for (int j = 0; j < LW; ++j) Sm[g][L][j] = S[j] * inv;
  }
  __syncthreads();

  if (L < LW) {  // lane L = column j: w_j = 2 * sum_l P[l][j], scatter
    float s = 0.f;
#pragma unroll
    for (int l = 0; l < LW; ++l) s += Sm[g][l][L];
    const float wj = 2.0f * s;
    atomicAdd(&CL[g][tokL[g][L]], wj);  // token slots may collide
    CL[g][32 + L] = wj;                 // position slots unique
  }
  __syncthreads();

  {  // hi/lo bf16 split into LDS (rows g, padded stride 72)
    float4 cv = *reinterpret_cast<const float4*>(&CL[g][L * 4]);
    ushort4 hi, lo;
    hi.x = f2b(cv.x); hi.y = f2b(cv.y); hi.z = f2b(cv.z); hi.w = f2b(cv.w);
    lo.x = f2b(cv.x - b2f(hi.x)); lo.y = f2b(cv.y - b2f(hi.y));
    lo.z = f2b(cv.z - b2f(hi.z)); lo.w = f2b(cv.w - b2f(hi.w));
    *reinterpret_cast<ushort4*>(CLh + g * 72 + L * 4) = hi;
    *reinterpret_cast<ushort4*>(CLl + g * 72 + L * 4) = lo;
  }
  __syncthreads();

  // Phase B: wave w covers cols cb0 + w*64 .. +63 of all 16 moves.
  floatx4 acc[4];
#pragma unroll
  for (int i = 0; i < 4; ++i) acc[i] = (floatx4){0.f, 0.f, 0.f, 0.f};

#pragma unroll
  for (int ksi = 0; ksi < 2; ++ksi) {
    const int ks = ksi * 32;
    short8 ah = *reinterpret_cast<const short8*>(CLh + l16 * 72 + ks + quad * 8);
    short8 al = *reinterpret_cast<const short8*>(CLl + l16 * 72 + ks + quad * 8);
#pragma unroll
    for (int ni = 0; ni < 4; ++ni) {
      acc[ni] = __builtin_amdgcn_mfma_f32_16x16x32_bf16(ah, bfrag[ksi][ni], acc[ni], 0, 0, 0);
      acc[ni] = __builtin_amdgcn_mfma_f32_16x16x32_bf16(al, bfrag[ksi][ni], acc[ni], 0, 0, 0);
    }
  }

#pragma unroll
  for (int ni = 0; ni < 4; ++ni) {
    const int gcol = colb + ni * 16 + l16;
    const float bias30 = 30.0f * bv[gcol];
#pragma unroll
    for (int i = 0; i < 4; ++i) {
      out[(size_t)(m0 + quad * 4 + i) * DIM + gcol] = acc[ni][i] + bias30;
    }
  }
}

// ---------------------------------------------------------------------------
extern "C" void kernel_launch(void* const* d_in, const int* in_sizes, int n_in,
                              void* d_out, int out_size, void* d_ws, size_t ws_size,
                              hipStream_t stream) {
  const void*  tokens = d_in[0];
  const float* letter = (const float*)d_in[1];
  const float* pos    = (const float*)d_in[2];
  const float* Wq     = (const float*)d_in[3];
  const float* bq     = (const float*)d_in[4];
  const float* Wk     = (const float*)d_in[5];
  const float* bk     = (const float*)d_in[6];
  const float* Wv     = (const float*)d_in[7];
  const float* bv     = (const float*)d_in[8];
  float*       outp   = (float*)d_out;   // reference output dtype = float32

  char* ws = (char*)d_ws;
  const size_t XP_SZ  = (size_t)12 * PLSZ * 4;      // 12 planes  = 2.25 MB
  const size_t G_SZ   = (size_t)XROW * 64 * 4;      // 12 KB
  float*          Xp  = (float*)(ws);
  float*          Gp  = (float*)(ws + XP_SZ);
  unsigned short* XvT = (unsigned short*)(ws + XP_SZ + G_SZ);

  proj_ksplit<<<dim3(KSPL, 16, 3), 256, 0, stream>>>(letter, pos, Wq, Wk, Wv,
                                                     Xp, Gp);
  gram_vexp<<<GSPL + 16, 256, 0, stream>>>(Xp, bq, bk, Gp, XvT);
  attn_gemm<<<dim3(NMOVES / 16, 4), 256, 0, stream>>>(tokens, Gp, XvT, bv, outp);
}